// Round 1
// baseline (676.521 us; speedup 1.0000x reference)
//
#include <hip/hip_runtime.h>

#define BB   16
#define SS   512
#define DD   1024
#define HH   16
#define DKK  64
#define DFFN 4096
#define LN_EPS 1e-6f

typedef __attribute__((ext_vector_type(8))) __bf16 bf16x8;
typedef __attribute__((ext_vector_type(4))) float f32x4;
typedef __attribute__((ext_vector_type(8))) unsigned short ushort8;
typedef __attribute__((ext_vector_type(4))) unsigned short ushort4_t;

#define AS1 __attribute__((address_space(1)))
#define AS3 __attribute__((address_space(3)))

__device__ __forceinline__ unsigned short f2bf(float f) {
  unsigned int u = __float_as_uint(f);
  u += 0x7FFFu + ((u >> 16) & 1u);   // round-nearest-even
  return (unsigned short)(u >> 16);
}

__device__ __forceinline__ float gelu_f(float x) {
  float x3 = x * x * x;
  return 0.5f * x * (1.0f + tanhf(0.7978845608028654f * (x + 0.044715f * x3)));
}

// ---------------- LayerNorm: fp32 in -> bf16 out (torch-style unbiased std, eps on std)
__global__ __launch_bounds__(256) void ln_kernel(const float* __restrict__ x,
                                                 const float* __restrict__ g,
                                                 const float* __restrict__ b,
                                                 unsigned short* __restrict__ out) {
  const int row = blockIdx.x;
  const int tid = threadIdx.x;
  const float* xr = x + (size_t)row * DD;
  float4 v = *(const float4*)(xr + tid * 4);
  float s = v.x + v.y + v.z + v.w;
#pragma unroll
  for (int off = 1; off < 64; off <<= 1) s += __shfl_xor(s, off);
  __shared__ float red[8];
  const int wid = tid >> 6, l = tid & 63;
  if (l == 0) red[wid] = s;
  __syncthreads();
  const float mean = (red[0] + red[1] + red[2] + red[3]) * (1.0f / DD);
  float4 d;
  d.x = v.x - mean; d.y = v.y - mean; d.z = v.z - mean; d.w = v.w - mean;
  float ss = d.x * d.x + d.y * d.y + d.z * d.z + d.w * d.w;
#pragma unroll
  for (int off = 1; off < 64; off <<= 1) ss += __shfl_xor(ss, off);
  if (l == 0) red[4 + wid] = ss;
  __syncthreads();
  const float var = (red[4] + red[5] + red[6] + red[7]) * (1.0f / (DD - 1));
  const float scale = 1.0f / (sqrtf(var) + LN_EPS);
  float4 gv = *(const float4*)(g + tid * 4);
  float4 bv = *(const float4*)(b + tid * 4);
  ushort4_t o;
  o[0] = f2bf(gv.x * d.x * scale + bv.x);
  o[1] = f2bf(gv.y * d.y * scale + bv.y);
  o[2] = f2bf(gv.z * d.z * scale + bv.z);
  o[3] = f2bf(gv.w * d.w * scale + bv.w);
  *(ushort4_t*)(out + (size_t)row * DD + tid * 4) = o;
}

// ---------------- fp32 -> bf16 elementwise (8/thread)
__global__ __launch_bounds__(256) void cvt_bf16(const float* __restrict__ in,
                                                unsigned short* __restrict__ out, int n8) {
  int i = blockIdx.x * 256 + threadIdx.x;
  if (i >= n8) return;
  const float4* p = (const float4*)(in + (size_t)i * 8);
  float4 a = p[0], b = p[1];
  ushort8 o;
  o[0] = f2bf(a.x); o[1] = f2bf(a.y); o[2] = f2bf(a.z); o[3] = f2bf(a.w);
  o[4] = f2bf(b.x); o[5] = f2bf(b.y); o[6] = f2bf(b.z); o[7] = f2bf(b.w);
  *(ushort8*)(out + (size_t)i * 8) = o;
}

// ---------------- W[K][N] fp32 -> WT[N][K] bf16
__global__ __launch_bounds__(256) void transpose_cvt(const float* __restrict__ W,
                                                     unsigned short* __restrict__ WT,
                                                     int K, int N) {
  __shared__ float tile[32][33];
  const int tx = threadIdx.x & 31, ty = threadIdx.x >> 5;  // ty 0..7
  const int n0 = blockIdx.x * 32, k0 = blockIdx.y * 32;
#pragma unroll
  for (int i = 0; i < 32; i += 8)
    tile[ty + i][tx] = W[(size_t)(k0 + ty + i) * N + n0 + tx];
  __syncthreads();
#pragma unroll
  for (int i = 0; i < 32; i += 8)
    WT[(size_t)(n0 + ty + i) * K + k0 + tx] = f2bf(tile[tx][ty + i]);
}

// ---------------- GEMM: C[M][N] = A[M][K](bf16) @ BT[N][K](bf16)^T + bias (+epilogue)
// EPI 0: +bias -> bf16 out ; EPI 1: +bias+resid -> f32 out ; EPI 2: +bias, gelu -> bf16 out
#define GBM 128
#define GBN 128
#define GBK 64

template <int EPI>
__global__ __launch_bounds__(256) void gemm_bt(const unsigned short* __restrict__ A,
                                               const unsigned short* __restrict__ BT,
                                               const float* __restrict__ bias,
                                               const float* __restrict__ resid,
                                               void* __restrict__ Cout,
                                               int M, int N, int K) {
  __shared__ __align__(16) unsigned short smA[GBM * GBK];
  __shared__ __align__(16) unsigned short smB[GBN * GBK];
  const int tid = threadIdx.x;
  const int nb = N / GBN;
  const int mb = blockIdx.x / nb;
  const int nbk = blockIdx.x % nb;
  const int wid = tid >> 6, l = tid & 63;
  const int wr = wid >> 1, wc = wid & 1;
  const int lr = l & 15, lg = l >> 4;
  const int srow = tid >> 3;       // 0..31 (stage row within 32-row chunk)
  const int scol = (tid & 7) * 8;  // stage col (elements)

  f32x4 acc[4][4] = {};
  const unsigned short* Abase = A + (size_t)mb * GBM * K + (size_t)srow * K + scol;
  const unsigned short* Bbase = BT + (size_t)nbk * GBN * K + (size_t)srow * K + scol;

  for (int kt = 0; kt < K; kt += GBK) {
#pragma unroll
    for (int c = 0; c < 4; ++c)
      __builtin_amdgcn_global_load_lds((const AS1 void*)(Abase + kt + (size_t)c * 32 * K),
                                       (AS3 void*)(smA + c * 2048 + wid * 512), 16, 0, 0);
#pragma unroll
    for (int c = 0; c < 4; ++c)
      __builtin_amdgcn_global_load_lds((const AS1 void*)(Bbase + kt + (size_t)c * 32 * K),
                                       (AS3 void*)(smB + c * 2048 + wid * 512), 16, 0, 0);
    __syncthreads();
#pragma unroll
    for (int ks = 0; ks < 2; ++ks) {
      bf16x8 af[4], bfr[4];
#pragma unroll
      for (int mi = 0; mi < 4; ++mi)
        af[mi] = *(const bf16x8*)(smA + (wr * 64 + mi * 16 + lr) * GBK + ks * 32 + lg * 8);
#pragma unroll
      for (int ni = 0; ni < 4; ++ni)
        bfr[ni] = *(const bf16x8*)(smB + (wc * 64 + ni * 16 + lr) * GBK + ks * 32 + lg * 8);
#pragma unroll
      for (int mi = 0; mi < 4; ++mi)
#pragma unroll
        for (int ni = 0; ni < 4; ++ni)
          acc[mi][ni] = __builtin_amdgcn_mfma_f32_16x16x32_bf16(af[mi], bfr[ni], acc[mi][ni], 0, 0, 0);
    }
    __syncthreads();
  }

  const int colb = nbk * GBN + wc * 64;
  const int rowb = mb * GBM + wr * 64;
#pragma unroll
  for (int ni = 0; ni < 4; ++ni) {
    const int col = colb + ni * 16 + lr;
    const float bv = bias[col];
#pragma unroll
    for (int mi = 0; mi < 4; ++mi) {
#pragma unroll
      for (int j = 0; j < 4; ++j) {
        const int row = rowb + mi * 16 + lg * 4 + j;
        float vv = acc[mi][ni][j] + bv;
        if (EPI == 2) vv = gelu_f(vv);
        const size_t o = (size_t)row * N + col;
        if (EPI == 1) {
          ((float*)Cout)[o] = vv + resid[o];
        } else {
          ((unsigned short*)Cout)[o] = f2bf(vv);
        }
      }
    }
  }
}

// ---------------- Fused attention: per-(b,h,32-row q-tile) block, 4 waves.
// scores(regs, fp32) = q @ k1^T + q @ k2^T (combined), *1/8, mask, softmax,
// * sigmoid(mask_logits), -> P(LDS bf16) ; ctx = P @ V via MFMA (V transposed-staged).
__global__ __launch_bounds__(256) void attn_kernel(const unsigned short* __restrict__ q,
                                                   const unsigned short* __restrict__ k1,
                                                   const unsigned short* __restrict__ k2,
                                                   const unsigned short* __restrict__ v,
                                                   const int* __restrict__ mask,
                                                   const float* __restrict__ ml,
                                                   unsigned short* __restrict__ ctx) {
  __shared__ __align__(16) unsigned short qs[32 * 72];
  __shared__ __align__(16) unsigned short Ps[32 * 520];
  __shared__ __align__(16) unsigned short Vts[64 * 72];
  __shared__ float red[4 * 32];

  const int tid = threadIdx.x;
  const int bq = blockIdx.x;
  const int qt = bq & 15;
  const int h = (bq >> 4) & (HH - 1);
  const int b = bq >> 8;
  const int q0 = qt * 32;
  const int wid = tid >> 6, l = tid & 63;
  const int lr = l & 15, lg = l >> 4;
  const size_t bh_off = ((size_t)b * SS) * DD + h * DKK;

  {  // stage q tile 32x64
    const int row = tid >> 3, c0 = (tid & 7) * 8;
    *(ushort8*)(qs + row * 72 + c0) =
        *(const ushort8*)(q + bh_off + (size_t)(q0 + row) * DD + c0);
  }
  __syncthreads();

  bf16x8 af[2][2];
#pragma unroll
  for (int mi = 0; mi < 2; ++mi)
#pragma unroll
    for (int ks = 0; ks < 2; ++ks)
      af[mi][ks] = *(const bf16x8*)(qs + (mi * 16 + lr) * 72 + ks * 32 + lg * 8);

  f32x4 sc[2][8] = {};
#pragma unroll
  for (int ni = 0; ni < 8; ++ni) {
    const int key = wid * 128 + ni * 16 + lr;
    const unsigned short* k1p = k1 + bh_off + (size_t)key * DD;
    const unsigned short* k2p = k2 + bh_off + (size_t)key * DD;
#pragma unroll
    for (int ks = 0; ks < 2; ++ks) {
      bf16x8 bb1 = *(const bf16x8*)(k1p + ks * 32 + lg * 8);
      bf16x8 bb2 = *(const bf16x8*)(k2p + ks * 32 + lg * 8);
#pragma unroll
      for (int mi = 0; mi < 2; ++mi) {
        sc[mi][ni] = __builtin_amdgcn_mfma_f32_16x16x32_bf16(af[mi][ks], bb1, sc[mi][ni], 0, 0, 0);
        sc[mi][ni] = __builtin_amdgcn_mfma_f32_16x16x32_bf16(af[mi][ks], bb2, sc[mi][ni], 0, 0, 0);
      }
    }
  }

  // scale + mask + row max (over this wave's 128-col slice)
  float mx[2][4];
#pragma unroll
  for (int mi = 0; mi < 2; ++mi)
#pragma unroll
    for (int j = 0; j < 4; ++j) mx[mi][j] = -3e38f;
#pragma unroll
  for (int mi = 0; mi < 2; ++mi)
#pragma unroll
    for (int ni = 0; ni < 8; ++ni) {
      const int col = wid * 128 + ni * 16 + lr;
#pragma unroll
      for (int j = 0; j < 4; ++j) {
        const int rowg = q0 + mi * 16 + lg * 4 + j;
        float s = sc[mi][ni][j] * 0.125f;
        const int m = mask[((size_t)b * SS + rowg) * SS + col];
        s = (m == 0) ? -1e9f : s;
        sc[mi][ni][j] = s;
        mx[mi][j] = fmaxf(mx[mi][j], s);
      }
    }
#pragma unroll
  for (int mi = 0; mi < 2; ++mi)
#pragma unroll
    for (int j = 0; j < 4; ++j) {
      float m = mx[mi][j];
      m = fmaxf(m, __shfl_xor(m, 1));
      m = fmaxf(m, __shfl_xor(m, 2));
      m = fmaxf(m, __shfl_xor(m, 4));
      m = fmaxf(m, __shfl_xor(m, 8));
      mx[mi][j] = m;
    }
  if (lr == 0) {
#pragma unroll
    for (int mi = 0; mi < 2; ++mi)
#pragma unroll
      for (int j = 0; j < 4; ++j) red[wid * 32 + mi * 16 + lg * 4 + j] = mx[mi][j];
  }
  __syncthreads();
  float rmax[2][4], rsum[2][4];
#pragma unroll
  for (int mi = 0; mi < 2; ++mi)
#pragma unroll
    for (int j = 0; j < 4; ++j) {
      const int r = mi * 16 + lg * 4 + j;
      rmax[mi][j] = fmaxf(fmaxf(red[r], red[32 + r]), fmaxf(red[64 + r], red[96 + r]));
      rsum[mi][j] = 0.f;
    }
#pragma unroll
  for (int mi = 0; mi < 2; ++mi)
#pragma unroll
    for (int ni = 0; ni < 8; ++ni)
#pragma unroll
      for (int j = 0; j < 4; ++j) {
        const float p = __expf(sc[mi][ni][j] - rmax[mi][j]);
        sc[mi][ni][j] = p;
        rsum[mi][j] += p;
      }
#pragma unroll
  for (int mi = 0; mi < 2; ++mi)
#pragma unroll
    for (int j = 0; j < 4; ++j) {
      float s = rsum[mi][j];
      s += __shfl_xor(s, 1);
      s += __shfl_xor(s, 2);
      s += __shfl_xor(s, 4);
      s += __shfl_xor(s, 8);
      rsum[mi][j] = s;
    }
  __syncthreads();  // all max-reads of red done before reuse
  if (lr == 0) {
#pragma unroll
    for (int mi = 0; mi < 2; ++mi)
#pragma unroll
      for (int j = 0; j < 4; ++j) red[wid * 32 + mi * 16 + lg * 4 + j] = rsum[mi][j];
  }
  __syncthreads();
  float rinv[2][4];
#pragma unroll
  for (int mi = 0; mi < 2; ++mi)
#pragma unroll
    for (int j = 0; j < 4; ++j) {
      const int r = mi * 16 + lg * 4 + j;
      rinv[mi][j] = 1.0f / (red[r] + red[32 + r] + red[64 + r] + red[96 + r]);
    }
  // write P (normalized * sigmoid(mask_logits)) as bf16
#pragma unroll
  for (int mi = 0; mi < 2; ++mi)
#pragma unroll
    for (int ni = 0; ni < 8; ++ni) {
      const int col = wid * 128 + ni * 16 + lr;
#pragma unroll
      for (int j = 0; j < 4; ++j) {
        const int rl = mi * 16 + lg * 4 + j;
        const float mlv = ml[(size_t)(q0 + rl) * SS + col];
        const float sig = 1.0f / (1.0f + __expf(-mlv));
        Ps[rl * 520 + col] = f2bf(sc[mi][ni][j] * rinv[mi][j] * sig);
      }
    }

  // PV: each wave owns dk slice wid*16..+15, contracts all 512 keys
  f32x4 accc[2] = {};
  for (int kt = 0; kt < 8; ++kt) {
    __syncthreads();  // kt=0: P complete ; kt>0: previous Vts reads done
#pragma unroll
    for (int c = 0; c < 2; ++c) {
      const int e = tid * 2 + c;
      const int key = e >> 3;
      const int dk0 = (e & 7) * 8;
      ushort8 vv = *(const ushort8*)(v + bh_off + (size_t)(kt * 64 + key) * DD + dk0);
#pragma unroll
      for (int jj = 0; jj < 8; ++jj) Vts[(dk0 + jj) * 72 + key] = vv[jj];
    }
    __syncthreads();
#pragma unroll
    for (int ks = 0; ks < 2; ++ks) {
      bf16x8 vb = *(const bf16x8*)(Vts + (wid * 16 + lr) * 72 + ks * 32 + lg * 8);
#pragma unroll
      for (int mi = 0; mi < 2; ++mi) {
        bf16x8 pa = *(const bf16x8*)(Ps + (mi * 16 + lr) * 520 + kt * 64 + ks * 32 + lg * 8);
        accc[mi] = __builtin_amdgcn_mfma_f32_16x16x32_bf16(pa, vb, accc[mi], 0, 0, 0);
      }
    }
  }
#pragma unroll
  for (int mi = 0; mi < 2; ++mi)
#pragma unroll
    for (int j = 0; j < 4; ++j) {
      const int rowg = q0 + mi * 16 + lg * 4 + j;
      ctx[bh_off + (size_t)rowg * DD + wid * 16 + lr] = f2bf(accc[mi][j]);
    }
}

// ----------------------------------------------------------------------------
extern "C" void kernel_launch(void* const* d_in, const int* in_sizes, int n_in,
                              void* d_out, int out_size, void* d_ws, size_t ws_size,
                              hipStream_t stream) {
  (void)in_sizes; (void)n_in; (void)out_size; (void)ws_size;
  const float* x    = (const float*)d_in[0];
  const float* timep= (const float*)d_in[1];
  const float* Wq = (const float*)d_in[2];  const float* bq = (const float*)d_in[3];
  const float* Wk = (const float*)d_in[4];  const float* bk = (const float*)d_in[5];
  const float* Wt = (const float*)d_in[6];  const float* bt = (const float*)d_in[7];
  const float* Wv = (const float*)d_in[8];  const float* bv = (const float*)d_in[9];
  const float* Wo = (const float*)d_in[10]; const float* bo = (const float*)d_in[11];
  const float* W1 = (const float*)d_in[12]; const float* b1 = (const float*)d_in[13];
  const float* W2 = (const float*)d_in[14]; const float* b2 = (const float*)d_in[15];
  const float* ln1g = (const float*)d_in[16]; const float* ln1b = (const float*)d_in[17];
  const float* ln2g = (const float*)d_in[18]; const float* ln2b = (const float*)d_in[19];
  const float* ml   = (const float*)d_in[20];
  const int*   mask = (const int*)d_in[21];
  float* out = (float*)d_out;

  char* w = (char*)d_ws;
  auto alloc = [&](size_t sz) { char* p = w; w += (sz + 255) & ~(size_t)255; return p; };
  const int MT = BB * SS;  // 8192 rows

  unsigned short* WqT = (unsigned short*)alloc((size_t)DD * DD * 2);
  unsigned short* WkT = (unsigned short*)alloc((size_t)DD * DD * 2);
  unsigned short* WtT = (unsigned short*)alloc((size_t)DD * DD * 2);
  unsigned short* WvT = (unsigned short*)alloc((size_t)DD * DD * 2);
  unsigned short* WoT = (unsigned short*)alloc((size_t)DD * DD * 2);
  unsigned short* W1T = (unsigned short*)alloc((size_t)DD * DFFN * 2);   // [DFFN][DD]
  unsigned short* W2T = (unsigned short*)alloc((size_t)DFFN * DD * 2);   // [DD][DFFN]
  unsigned short* xn  = (unsigned short*)alloc((size_t)MT * DD * 2);
  unsigned short* tb  = (unsigned short*)alloc((size_t)MT * DD * 2);     // time bf16, reused as ctx
  unsigned short* qb  = (unsigned short*)alloc((size_t)MT * DD * 2);
  unsigned short* k1b = (unsigned short*)alloc((size_t)MT * DD * 2);
  unsigned short* k2b = (unsigned short*)alloc((size_t)MT * DD * 2);
  unsigned short* vbf = (unsigned short*)alloc((size_t)MT * DD * 2);
  float*          x2  = (float*)alloc((size_t)MT * DD * 4);
  unsigned short* hb  = (unsigned short*)alloc((size_t)MT * DFFN * 2);
  unsigned short* xn2 = xn;   // xn dead after q/k1/v projections
  unsigned short* ctx = tb;   // tb dead after k2 projection

  // weight transpose+convert
  transpose_cvt<<<dim3(DD / 32, DD / 32), 256, 0, stream>>>(Wq, WqT, DD, DD);
  transpose_cvt<<<dim3(DD / 32, DD / 32), 256, 0, stream>>>(Wk, WkT, DD, DD);
  transpose_cvt<<<dim3(DD / 32, DD / 32), 256, 0, stream>>>(Wt, WtT, DD, DD);
  transpose_cvt<<<dim3(DD / 32, DD / 32), 256, 0, stream>>>(Wv, WvT, DD, DD);
  transpose_cvt<<<dim3(DD / 32, DD / 32), 256, 0, stream>>>(Wo, WoT, DD, DD);
  transpose_cvt<<<dim3(DFFN / 32, DD / 32), 256, 0, stream>>>(W1, W1T, DD, DFFN);
  transpose_cvt<<<dim3(DD / 32, DFFN / 32), 256, 0, stream>>>(W2, W2T, DFFN, DD);

  cvt_bf16<<<dim3((MT * DD / 8) / 256), 256, 0, stream>>>(timep, tb, MT * DD / 8);
  ln_kernel<<<dim3(MT), 256, 0, stream>>>(x, ln1g, ln1b, xn);

  // projections
  gemm_bt<0><<<dim3((MT / GBM) * (DD / GBN)), 256, 0, stream>>>(xn, WqT, bq, nullptr, (void*)qb, MT, DD, DD);
  gemm_bt<0><<<dim3((MT / GBM) * (DD / GBN)), 256, 0, stream>>>(xn, WkT, bk, nullptr, (void*)k1b, MT, DD, DD);
  gemm_bt<0><<<dim3((MT / GBM) * (DD / GBN)), 256, 0, stream>>>(tb, WtT, bt, nullptr, (void*)k2b, MT, DD, DD);
  gemm_bt<0><<<dim3((MT / GBM) * (DD / GBN)), 256, 0, stream>>>(xn, WvT, bv, nullptr, (void*)vbf, MT, DD, DD);

  attn_kernel<<<dim3(BB * HH * 16), 256, 0, stream>>>(qb, k1b, k2b, vbf, mask, ml, ctx);

  gemm_bt<1><<<dim3((MT / GBM) * (DD / GBN)), 256, 0, stream>>>(ctx, WoT, bo, x, (void*)x2, MT, DD, DD);
  ln_kernel<<<dim3(MT), 256, 0, stream>>>(x2, ln2g, ln2b, xn2);
  gemm_bt<2><<<dim3((MT / GBM) * (DFFN / GBN)), 256, 0, stream>>>(xn2, W1T, b1, nullptr, (void*)hb, MT, DFFN, DD);
  gemm_bt<1><<<dim3((MT / GBM) * (DD / GBN)), 256, 0, stream>>>(hb, W2T, b2, x2, (void*)out, MT, DD, DFFN);
}